// Round 11
// baseline (21.908 us; speedup 1.0000x reference)
//
#include <hip/hip_runtime.h>
#include <stdint.h>

// InstanceLoss: loss = sum_{lab[i]==lab[j], i!=j} ||e_i - e_j + EPS|| / (N*(N-1))
// dist^2 = n_i + n_j - 2*G_ij (EPS terms ~1e-10, far below the 7e-3 threshold).
// Labels in [0,64) -> only within-group pairs. Pipeline, each phase at its
// natural parallelism (r9/r10 lesson: one 192-block kernel serializes the
// scan+scattered-gather chain in every block):
//  K1 k_scan    (64 blocks): ballot-rank scan -> inv[] permutation, goff/gcnt.
//  K2 k_convert (2048 blocks): coalesced E read -> bf16 scatter-store into
//               grouped-contiguous E16g + row norms qg (stores don't stall).
//  K3 k_gram    (256 blocks = 64 groups x 4 quadrants): CONTIGUOUS staging via
//               global_load_lds w=16 (pre-swizzled source granules), diag
//               quadrants stage once; MFMA slab; fused dist+mask+reduce;
//               plain partial store (no contended ticket).
//  K4 k_final   : 1-wave fixed-order double reduce.

#define NROWS 8192
#define DDIM 256
#define NLAB 64
#define NQUAD (NLAB * 4)

typedef __attribute__((ext_vector_type(8))) short bfrag8;
typedef __attribute__((ext_vector_type(4))) float f32x4;

__device__ __forceinline__ unsigned short f2bf(float f) {
  unsigned u = __float_as_uint(f);
  u += 0x7FFFu + ((u >> 16) & 1u);   // RNE
  return (unsigned short)(u >> 16);
}

__device__ __forceinline__ float bf2f(unsigned short h) {
  return __uint_as_float(((unsigned)h) << 16);
}

__device__ __forceinline__ void async_cp16(const void* gsrc, void* ldst) {
  __builtin_amdgcn_global_load_lds(
      (const __attribute__((address_space(1))) void*)gsrc,
      (__attribute__((address_space(3))) void*)ldst, 16, 0, 0);
}

// K1: block g computes grouped positions for rows of label g.
// inv[row] = goff[g] + rank (inv is a permutation of 0..NROWS-1).
__global__ void __launch_bounds__(512)
k_scan(const int* __restrict__ lab, int* __restrict__ inv,
       int* __restrict__ goff, int* __restrict__ gcnt) {
  __shared__ int labS[NROWS];        // 32 KB
  __shared__ int wcntS[8], wltS[8];
  const int g = blockIdx.x, t = threadIdx.x, l = t & 63, w = t >> 6;
  {
    const int4* src = (const int4*)lab;
    int4* dst = (int4*)labS;
    #pragma unroll
    for (int i = 0; i < 4; ++i) dst[t + 512 * i] = src[t + 512 * i];
  }
  __syncthreads();
  int cntw = 0, ltw = 0;
  for (int c = w * 16; c < w * 16 + 16; ++c) {
    const int lv = labS[c * 64 + l];
    cntw += (int)__popcll(__ballot(lv == g));
    ltw += (lv < g) ? 1 : 0;
  }
  #pragma unroll
  for (int o = 32; o; o >>= 1) ltw += __shfl_down(ltw, o);
  if (l == 0) { wcntS[w] = cntw; wltS[w] = ltw; }
  __syncthreads();
  int base = 0, nt = 0, off = 0;
  #pragma unroll
  for (int w2 = 0; w2 < 8; ++w2) {
    nt += wcntS[w2];
    off += wltS[w2];
    base += (w2 < w) ? wcntS[w2] : 0;
  }
  for (int c = w * 16; c < w * 16 + 16; ++c) {
    const int lv = labS[c * 64 + l];
    const unsigned long long m = __ballot(lv == g);
    if (lv == g) {
      const int rank = base + (int)__popcll(m & ((1ull << l) - 1ull));
      inv[c * 64 + l] = off + rank;
    }
    base += (int)__popcll(m);
  }
  if (t == 0) { goff[g] = off; gcnt[g] = nt; }
}

// K2: coalesced read of E row, bf16 convert, scatter-store to grouped layout.
__global__ void __launch_bounds__(256)
k_convert(const float* __restrict__ E, const int* __restrict__ inv,
          unsigned short* __restrict__ E16g, float* __restrict__ qg) {
  const int t = threadIdx.x, l = t & 63, w = t >> 6;
  const int row = blockIdx.x * 4 + w;
  const int pos = inv[row];                       // broadcast (same addr/wave)
  const float4 v = *reinterpret_cast<const float4*>(E + (size_t)row * DDIM + l * 4);
  ushort4 b4;
  b4.x = f2bf(v.x); b4.y = f2bf(v.y); b4.z = f2bf(v.z); b4.w = f2bf(v.w);
  *reinterpret_cast<ushort4*>(E16g + (size_t)pos * DDIM + l * 4) = b4;
  const float f0 = bf2f(b4.x), f1 = bf2f(b4.y);
  const float f2 = bf2f(b4.z), f3 = bf2f(b4.w);
  float q = f0 * f0 + f1 * f1 + f2 * f2 + f3 * f3;
  #pragma unroll
  for (int o = 32; o; o >>= 1) q += __shfl_down(q, o);
  if (l == 0) qg[pos] = q;
}

// K3: 64 groups x 4 quadrants (hi,hj); contiguous global_load_lds staging
// (linear LDS dest, source granule pre-XORed); diag quadrants stage once.
__global__ void __launch_bounds__(512)
k_gram(const unsigned short* __restrict__ E16g, const float* __restrict__ qg,
       const int* __restrict__ goff, const int* __restrict__ gcnt,
       float* __restrict__ partials) {
  __shared__ __align__(16) char As[128 * 512];   // 64 KB (128 rows x 256 bf16)
  __shared__ __align__(16) char Bs[128 * 512];   // 64 KB (off-diag only)
  __shared__ float qA[128], qB[128];
  __shared__ float wsum[8];

  const int bid = blockIdx.x;
  const int g = bid >> 2, hi = (bid >> 1) & 1, hj = bid & 1;
  const int t = threadIdx.x, l = t & 63, w = t >> 6;   // 8 waves
  const int off = goff[g];
  const int n = min(gcnt[g], 256);
  const bool diag = (hi == hj);
  float blocksum = 0.f;

  if ((hi * 128 < n) && (hj * 128 < n)) {
    if (t < 128) {
      const int gi = hi * 128 + t;
      qA[t] = qg[off + ((gi < n) ? gi : 0)];
    } else if (t < 256 && !diag) {
      const int c = t - 128;
      const int gj = hj * 128 + c;
      qB[c] = qg[off + ((gj < n) ? gj : 0)];
    }
    // stage: wave w covers local rows [w*16, w*16+16); each async covers 2
    // rows (64 lanes x 16B). Linear LDS dest; source granule lg=(l&31)^(rl&15).
    #pragma unroll
    for (int i = 0; i < 8; ++i) {
      const int rl = w * 16 + 2 * i + (l >> 5);
      const int lg = (l & 31) ^ (rl & 15);
      const int ga = hi * 128 + rl;
      const int sa = off + ((ga < n) ? ga : 0);
      async_cp16(E16g + (size_t)sa * DDIM + lg * 8, As + (w * 16 + 2 * i) * 512);
      if (!diag) {
        const int gb = hj * 128 + rl;
        const int sb = off + ((gb < n) ? gb : 0);
        async_cp16(E16g + (size_t)sb * DDIM + lg * 8, Bs + (w * 16 + 2 * i) * 512);
      }
    }
    __syncthreads();

    // MFMA: 8 waves as 2x4; per wave 64x32 out = 4x2 frags; K=256 in 8 steps
    const char* Bbuf = diag ? As : Bs;
    const float* qBp = diag ? qA : qB;
    const int wr = w >> 2, wc = w & 3;
    const int colsel = l & 15;
    const int ksel = l >> 4;

    f32x4 acc[4][2];
    const f32x4 zero = {0.f, 0.f, 0.f, 0.f};
    #pragma unroll
    for (int m = 0; m < 4; ++m)
      #pragma unroll
      for (int nn = 0; nn < 2; ++nn)
        acc[m][nn] = zero;

    #pragma unroll
    for (int kk = 0; kk < 8; ++kk) {
      bfrag8 af[4], bf[2];
      #pragma unroll
      for (int m = 0; m < 4; ++m) {
        const int row = wr * 64 + m * 16 + colsel;
        const int gidx = (kk * 4 + ksel) ^ (row & 15);
        af[m] = *reinterpret_cast<const bfrag8*>(As + row * 512 + (gidx << 4));
      }
      #pragma unroll
      for (int nn = 0; nn < 2; ++nn) {
        const int row = wc * 32 + nn * 16 + colsel;
        const int gidx = (kk * 4 + ksel) ^ (row & 15);
        bf[nn] = *reinterpret_cast<const bfrag8*>(Bbuf + row * 512 + (gidx << 4));
      }
      #pragma unroll
      for (int m = 0; m < 4; ++m)
        #pragma unroll
        for (int nn = 0; nn < 2; ++nn)
          acc[m][nn] = __builtin_amdgcn_mfma_f32_16x16x32_bf16(af[m], bf[nn],
                                                               acc[m][nn], 0, 0, 0);
    }

    // epilogue: C layout col(lane&15)=B row, row((lane>>4)*4+reg)=A row
    float lsum = 0.f;
    #pragma unroll
    for (int m = 0; m < 4; ++m) {
      const int ar = wr * 64 + m * 16 + ksel * 4;
      const int gi = hi * 128 + ar;
      const float q0 = qA[ar], q1 = qA[ar + 1], q2 = qA[ar + 2], q3 = qA[ar + 3];
      #pragma unroll
      for (int nn = 0; nn < 2; ++nn) {
        const int br = wc * 32 + nn * 16 + colsel;
        const int gj = hj * 128 + br;
        const bool jv = gj < n;
        const float qj = qBp[br];
        const f32x4 a = acc[m][nn];
        const float d0 = __builtin_amdgcn_sqrtf(fmaxf(q0 + qj - 2.f * a[0], 0.f));
        const float d1 = __builtin_amdgcn_sqrtf(fmaxf(q1 + qj - 2.f * a[1], 0.f));
        const float d2 = __builtin_amdgcn_sqrtf(fmaxf(q2 + qj - 2.f * a[2], 0.f));
        const float d3 = __builtin_amdgcn_sqrtf(fmaxf(q3 + qj - 2.f * a[3], 0.f));
        if (jv) {
          lsum += (gi + 0 < n && gi + 0 != gj) ? d0 : 0.f;
          lsum += (gi + 1 < n && gi + 1 != gj) ? d1 : 0.f;
          lsum += (gi + 2 < n && gi + 2 != gj) ? d2 : 0.f;
          lsum += (gi + 3 < n && gi + 3 != gj) ? d3 : 0.f;
        }
      }
    }
    #pragma unroll
    for (int o = 32; o; o >>= 1) lsum += __shfl_down(lsum, o);
    if (l == 0) wsum[w] = lsum;
    __syncthreads();
    blocksum = wsum[0] + wsum[1] + wsum[2] + wsum[3] +
               wsum[4] + wsum[5] + wsum[6] + wsum[7];
  }

  if (t == 0) partials[bid] = blocksum;
}

// K4: 1-wave deterministic final reduction (256 partials, fixed order, double).
__global__ void __launch_bounds__(64)
k_final(const float* __restrict__ partials, float* __restrict__ out, double invn) {
  const int l = threadIdx.x;
  double s = (double)partials[l] + (double)partials[l + 64] +
             (double)partials[l + 128] + (double)partials[l + 192];
  #pragma unroll
  for (int o = 32; o; o >>= 1) s += __shfl_down(s, o);
  if (l == 0) out[0] = (float)(s * invn);
}

extern "C" void kernel_launch(void* const* d_in, const int* in_sizes, int n_in,
                              void* d_out, int out_size, void* d_ws, size_t ws_size,
                              hipStream_t stream) {
  const float* E = (const float*)d_in[0];
  const int* lab = (const int*)d_in[1];
  float* out = (float*)d_out;
  (void)n_in; (void)in_sizes; (void)out_size; (void)ws_size;

  char* ws = (char*)d_ws;
  unsigned short* E16g = (unsigned short*)ws;            // 4 MB grouped bf16
  ws += (size_t)NROWS * DDIM * sizeof(unsigned short);
  float* qg = (float*)ws;   ws += NROWS * sizeof(float);
  int* inv = (int*)ws;      ws += NROWS * sizeof(int);
  int* goff = (int*)ws;     ws += NLAB * sizeof(int);
  int* gcnt = (int*)ws;     ws += NLAB * sizeof(int);
  float* partials = (float*)ws;                          // NQUAD floats

  const double invn = 1.0 / ((double)NROWS * (double)(NROWS - 1));
  k_scan<<<NLAB, 512, 0, stream>>>(lab, inv, goff, gcnt);
  k_convert<<<NROWS / 4, 256, 0, stream>>>(E, inv, E16g, qg);
  k_gram<<<NQUAD, 512, 0, stream>>>(E16g, qg, goff, gcnt, partials);
  k_final<<<1, 64, 0, stream>>>(partials, out, invn);
}

// Round 12
// 16.173 us; speedup vs baseline: 1.3546x; 1.3546x over previous
//
#include <hip/hip_runtime.h>
#include <stdint.h>

// InstanceLoss: loss = sum_{lab[i]==lab[j], i!=j} ||e_i - e_j + EPS|| / (N*(N-1))
// dist^2 = n_i + n_j - 2*G_ij (EPS terms ~1e-10, far below the 7e-3 threshold).
// Labels in [0,64) -> only within-group pairs. r12 = r9 (best, 16.6us) with:
//  (a) register-resident label scan (no LDS label stage, one fewer barrier)
//  (b) diag staging dedup + unroll-8 deep-MLP gather on both paths
//  (c) sumsq->MFMA barrier removed (both only READ the tiles; barrier moved
//      to post-MFMA, right before the epilogue needs qAS/qBS)
// Partials via plain store + tiny k_final (no contended ticket — r9 lesson).

#define NROWS 8192
#define DDIM 256
#define NLAB 64
#define NTILEB (NLAB * 3)

typedef __attribute__((ext_vector_type(8))) short bfrag8;
typedef __attribute__((ext_vector_type(4))) float f32x4;

__device__ __forceinline__ unsigned short f2bf(float f) {
  unsigned u = __float_as_uint(f);
  u += 0x7FFFu + ((u >> 16) & 1u);   // RNE
  return (unsigned short)(u >> 16);
}

__global__ void __launch_bounds__(512)
k_fused(const float* __restrict__ E, const int* __restrict__ lab,
        float* __restrict__ partials) {
  // A/B tiles: 128 rows x 256 bf16 (512 B rows; granule g stored at g^(row&15))
  __shared__ __align__(16) char As[128 * 512];   // 64 KB
  __shared__ __align__(16) char Bs[128 * 512];   // 64 KB (p==1 only)
  __shared__ int rowlistS[256];
  __shared__ float qAS[128], qBS[128];
  __shared__ int wcntS[8];
  __shared__ float wsum[8];

  const int bid = blockIdx.x;
  const int g = bid / 3, p = bid % 3;
  const int t = threadIdx.x, l = t & 63, w = t >> 6;   // 8 waves
  const int tit = (p == 2) ? 1 : 0, tjt = (p == 0) ? 0 : 1;
  const bool diag = (p != 1);

  // ---- (a) labels straight to registers: wave w owns chunks w*16..w*16+15 ----
  int lv[16];
  #pragma unroll
  for (int i = 0; i < 16; ++i)
    lv[i] = lab[(w * 16 + i) * 64 + l];            // coalesced 256B per chunk

  int cntw = 0;
  #pragma unroll
  for (int i = 0; i < 16; ++i)
    cntw += (int)__popcll(__ballot(lv[i] == g));
  if (l == 0) wcntS[w] = cntw;
  if (t == 0) rowlistS[0] = 0;                     // n==0 safety
  __syncthreads();
  int n_total = 0, base = 0;
  #pragma unroll
  for (int w2 = 0; w2 < 8; ++w2) {
    const int c = wcntS[w2];
    n_total += c;
    base += (w2 < w) ? c : 0;
  }
  #pragma unroll
  for (int i = 0; i < 16; ++i) {
    const unsigned long long m = __ballot(lv[i] == g);
    if (lv[i] == g) {
      const int rank = base + (int)__popcll(m & ((1ull << l) - 1ull));
      if (rank < 256) rowlistS[rank] = (w * 16 + i) * 64 + l;
    }
    base += (int)__popcll(m);
  }
  const int n = min(n_total, 256);
  __syncthreads();   // rowlist ready

  float blocksum = 0.f;
  const bool empty = (p != 0 && n <= 128);
  if (!empty) {
    // ---- (b) stage: f32 -> bf16, swizzled ds_write (both-sides XOR) ----
    const int gsw = l >> 1;          // granule 0..31 (16 B each)
    const int half8 = (l & 1) * 8;   // byte offset within granule
    if (diag) {
      #pragma unroll 8
      for (int r8 = 0; r8 < 16; ++r8) {
        const int r = w * 16 + r8;
        const int li = tit * 128 + r;
        const int grow = rowlistS[(li < n) ? li : 0];
        const float4 v = *reinterpret_cast<const float4*>(E + (size_t)grow * DDIM + l * 4);
        ushort4 b4;
        b4.x = f2bf(v.x); b4.y = f2bf(v.y); b4.z = f2bf(v.z); b4.w = f2bf(v.w);
        *reinterpret_cast<ushort4*>(
            As + r * 512 + ((gsw ^ (r & 15)) << 4) + half8) = b4;
      }
    } else {
      #pragma unroll 8
      for (int r8 = 0; r8 < 16; ++r8) {
        const int r = w * 16 + r8;
        const int growA = rowlistS[(r < n) ? r : 0];
        const int growB = rowlistS[(128 + r < n) ? 128 + r : 0];
        const float4 va = *reinterpret_cast<const float4*>(E + (size_t)growA * DDIM + l * 4);
        const float4 vb = *reinterpret_cast<const float4*>(E + (size_t)growB * DDIM + l * 4);
        ushort4 ba, bb;
        ba.x = f2bf(va.x); ba.y = f2bf(va.y); ba.z = f2bf(va.z); ba.w = f2bf(va.w);
        bb.x = f2bf(vb.x); bb.y = f2bf(vb.y); bb.z = f2bf(vb.z); bb.w = f2bf(vb.w);
        const int off = r * 512 + ((gsw ^ (r & 15)) << 4) + half8;
        *reinterpret_cast<ushort4*>(As + off) = ba;
        *reinterpret_cast<ushort4*>(Bs + off) = bb;
      }
    }
    __syncthreads();   // tiles staged

    // ---- per-row sumsq from staged bf16 (writes qAS/qBS; no barrier after:
    //      MFMA below only READS As/Bs; epilogue barrier covers qAS/qBS) ----
    if (diag) {
      const int r = t >> 2, q4 = t & 3;
      float q = 0.f;
      #pragma unroll
      for (int i = 0; i < 8; ++i) {
        const int gidx = q4 * 8 + i;
        const bfrag8 v = *reinterpret_cast<const bfrag8*>(
            As + r * 512 + ((gidx ^ (r & 15)) << 4));
        #pragma unroll
        for (int e = 0; e < 8; ++e) {
          const float f = __uint_as_float(((unsigned)(unsigned short)v[e]) << 16);
          q = fmaf(f, f, q);
        }
      }
      q += __shfl_xor(q, 1);
      q += __shfl_xor(q, 2);
      if ((t & 3) == 0) qAS[r] = q;
    } else {
      const int rAll = t >> 1, hf = t & 1;
      const int r = rAll & 127;
      const char* buf = (rAll < 128) ? As : Bs;
      float q = 0.f;
      #pragma unroll
      for (int i = 0; i < 16; ++i) {
        const int gidx = hf * 16 + i;
        const bfrag8 v = *reinterpret_cast<const bfrag8*>(
            buf + r * 512 + ((gidx ^ (r & 15)) << 4));
        #pragma unroll
        for (int e = 0; e < 8; ++e) {
          const float f = __uint_as_float(((unsigned)(unsigned short)v[e]) << 16);
          q = fmaf(f, f, q);
        }
      }
      q += __shfl_xor(q, 1);
      if (hf == 0) { if (rAll < 128) qAS[r] = q; else qBS[r] = q; }
    }

    // ---- MFMA: 8 waves as 2x4; per wave 64x32 output = 4x2 frags; K=256 ----
    const char* Bbuf = diag ? As : Bs;
    const float* qBp = diag ? qAS : qBS;
    const int wr = w >> 2, wc = w & 3;
    const int colsel = l & 15;
    const int ksel = l >> 4;

    f32x4 acc[4][2];
    const f32x4 zero = {0.f, 0.f, 0.f, 0.f};
    #pragma unroll
    for (int m = 0; m < 4; ++m)
      #pragma unroll
      for (int nn = 0; nn < 2; ++nn)
        acc[m][nn] = zero;

    #pragma unroll
    for (int kk = 0; kk < 8; ++kk) {
      bfrag8 af[4], bf[2];
      #pragma unroll
      for (int m = 0; m < 4; ++m) {
        const int row = wr * 64 + m * 16 + colsel;
        const int gidx = (kk * 4 + ksel) ^ (row & 15);
        af[m] = *reinterpret_cast<const bfrag8*>(As + row * 512 + (gidx << 4));
      }
      #pragma unroll
      for (int nn = 0; nn < 2; ++nn) {
        const int row = wc * 32 + nn * 16 + colsel;
        const int gidx = (kk * 4 + ksel) ^ (row & 15);
        bf[nn] = *reinterpret_cast<const bfrag8*>(Bbuf + row * 512 + (gidx << 4));
      }
      #pragma unroll
      for (int m = 0; m < 4; ++m)
        #pragma unroll
        for (int nn = 0; nn < 2; ++nn)
          acc[m][nn] = __builtin_amdgcn_mfma_f32_16x16x32_bf16(af[m], bf[nn],
                                                               acc[m][nn], 0, 0, 0);
    }
    __syncthreads();   // qAS/qBS now guaranteed complete for the epilogue

    // ---- epilogue: dist + validity/diag mask + reduce ----
    // C layout: col(lane&15)=B row, row((lane>>4)*4+reg)=A row [verified r1-11]
    float lsum = 0.f;
    #pragma unroll
    for (int m = 0; m < 4; ++m) {
      const int ib = wr * 64 + m * 16 + ksel * 4;    // local A row base
      const float q0 = qAS[ib], q1 = qAS[ib + 1], q2 = qAS[ib + 2], q3 = qAS[ib + 3];
      const int li = tit * 128 + ib;                 // in-group A index base
      #pragma unroll
      for (int nn = 0; nn < 2; ++nn) {
        const int jb = wc * 32 + nn * 16 + colsel;   // local B row
        const int lj = tjt * 128 + jb;               // in-group B index
        const bool jv = lj < n;
        const float qj = qBp[jb];
        const f32x4 a = acc[m][nn];
        const float d0 = __builtin_amdgcn_sqrtf(fmaxf(q0 + qj - 2.f * a[0], 0.f));
        const float d1 = __builtin_amdgcn_sqrtf(fmaxf(q1 + qj - 2.f * a[1], 0.f));
        const float d2 = __builtin_amdgcn_sqrtf(fmaxf(q2 + qj - 2.f * a[2], 0.f));
        const float d3 = __builtin_amdgcn_sqrtf(fmaxf(q3 + qj - 2.f * a[3], 0.f));
        if (jv) {
          lsum += (li + 0 < n && li + 0 != lj) ? d0 : 0.f;
          lsum += (li + 1 < n && li + 1 != lj) ? d1 : 0.f;
          lsum += (li + 2 < n && li + 2 != lj) ? d2 : 0.f;
          lsum += (li + 3 < n && li + 3 != lj) ? d3 : 0.f;
        }
      }
    }
    #pragma unroll
    for (int o = 32; o; o >>= 1) lsum += __shfl_down(lsum, o);
    if (l == 0) wsum[w] = lsum;
    __syncthreads();
    const float wgt = (p == 1) ? 2.0f : 1.0f;
    blocksum = wgt * (wsum[0] + wsum[1] + wsum[2] + wsum[3] +
                      wsum[4] + wsum[5] + wsum[6] + wsum[7]);
  }

  if (t == 0) partials[bid] = blocksum;
}

// 1-wave deterministic final reduction (192 partials, fixed order, double).
__global__ void __launch_bounds__(64)
k_final(const float* __restrict__ partials, float* __restrict__ out, double invn) {
  const int l = threadIdx.x;
  double s = (double)partials[l] + (double)partials[l + 64] +
             (double)partials[l + 128];
  #pragma unroll
  for (int o = 32; o; o >>= 1) s += __shfl_down(s, o);
  if (l == 0) out[0] = (float)(s * invn);
}

extern "C" void kernel_launch(void* const* d_in, const int* in_sizes, int n_in,
                              void* d_out, int out_size, void* d_ws, size_t ws_size,
                              hipStream_t stream) {
  const float* E = (const float*)d_in[0];
  const int* lab = (const int*)d_in[1];
  float* out = (float*)d_out;
  (void)n_in; (void)in_sizes; (void)out_size; (void)ws_size;

  float* partials = (float*)d_ws;   // NTILEB floats, fully rewritten every call

  const double invn = 1.0 / ((double)NROWS * (double)(NROWS - 1));
  k_fused<<<NTILEB, 512, 0, stream>>>(E, lab, partials);
  k_final<<<1, 64, 0, stream>>>(partials, out, invn);
}